// Round 9
// baseline (44.401 us; speedup 1.0000x reference)
//
#include <hip/hip_runtime.h>

#define SB 4096
#define BB 16
#define CC 512
#define RPB 8
#define CH 8

struct Small {
  int   fl_old[BB];
  int   fl_new[BB];
  float scale[BB];
};

// K1: per-batch (one 256-thr block per batch): mask-dtype detect (own 4KB
// region), masked cumsum (block scan), csum out, fire-position scatter
// S[b][r]=i (unclipped rint), llast defaults, tail=frac(total) -> scale,
// fl_old/fl_new, feat_lengths out. No cross-block dependencies.
__global__ void __launch_bounds__(256)
k_scan(const float* __restrict__ alphas, const void* __restrict__ mask,
       float* __restrict__ csum, int* __restrict__ S, Small* sm,
       float* __restrict__ out1, int T) {
  int b = blockIdx.x;
  int t = threadIdx.x;

  // mask dtype detect: scan only this batch's own uint8 region (1024 words).
  __shared__ int s_flag;
  if (t == 0) s_flag = 0;
  __syncthreads();
  {
    uint4 v = ((const uint4*)mask)[b * 256 + t];
    if ((v.x > 1u) || (v.y > 1u) || (v.z > 1u) || (v.w > 1u)) atomicOr(&s_flag, 1);
  }
  __syncthreads();
  int flag = s_flag;

  int lane = t & 63, wid = t >> 6;
  int base = t * 16;
  const float* ab = alphas + b * SB + base;
  float av[16];
#pragma unroll
  for (int k = 0; k < 16; k += 4) {
    float4 v = *(const float4*)(ab + k);
    av[k] = v.x; av[k + 1] = v.y; av[k + 2] = v.z; av[k + 3] = v.w;
  }
  unsigned mbits = 0;
  if (flag) {
    const unsigned char* mb = (const unsigned char*)mask + b * SB + base;
    uint4 mv = *(const uint4*)mb;
    unsigned mw[4] = {mv.x, mv.y, mv.z, mv.w};
#pragma unroll
    for (int k = 0; k < 16; ++k)
      if ((mw[k >> 2] >> ((k & 3) * 8)) & 0xFFu) { av[k] = 0.f; mbits |= 1u << k; }
  } else {
    const int* mi = (const int*)mask + b * SB + base;
#pragma unroll
    for (int k = 0; k < 16; ++k)
      if (mi[k]) { av[k] = 0.f; mbits |= 1u << k; }
  }

  float s = 0.f;
#pragma unroll
  for (int k = 0; k < 16; ++k) s += av[k];
  float si = s;
#pragma unroll
  for (int off = 1; off < 64; off <<= 1) {
    float v = __shfl_up(si, off);
    if (lane >= off) si += v;
  }
  __shared__ float wsum[4];
  if (lane == 63) wsum[wid] = si;
  __syncthreads();
  float woff = 0.f;
  for (int w = 0; w < wid; ++w) woff += wsum[w];
  float c = woff + (si - s);  // exclusive prefix
  float cs[16];
  float* cb = csum + b * SB + base;
#pragma unroll
  for (int k = 0; k < 16; ++k) { c += av[k]; cs[k] = c; cb[k] = c; }

  // exact previous csum: share each thread's final c via LDS
  __shared__ float cfin[256];
  __shared__ int   redl[4];
  int lmax = -1;
#pragma unroll
  for (int k = 0; k < 16; ++k) if (!((mbits >> k) & 1u)) lmax = base + k;
  cfin[t] = cs[15];
  for (int off = 32; off; off >>= 1) lmax = max(lmax, __shfl_down(lmax, off));
  if ((t & 63) == 0) redl[wid] = lmax;
  __syncthreads();
  int llast = max(max(redl[0], redl[1]), max(redl[2], redl[3]));
  float prevc = (t == 0) ? 0.f : cfin[t - 1];

  int* Sb = S + b * (T + RPB + 1);
  for (int j = t; j < T + RPB + 1; j += 256) Sb[j] = (j == 0) ? 0 : llast;
  __syncthreads();
  int p = (int)rintf(prevc);
#pragma unroll
  for (int k = 0; k < 16; ++k) {
    int r = (int)rintf(cs[k]);
    if (r != p && r < T + RPB + 1) Sb[r] = base + k;
    p = r;
  }

  if (t == 255) {
    float total = woff + si;
    float fl = floorf(total);
    float frac = total - fl;          // == tail_weights by mass conservation
    int e = (frac >= 0.5f) ? 1 : 0;
    int fli = (int)fl;
    sm->fl_old[b] = fli;
    sm->scale[b] = e ? (1.0f / frac) : 1.0f;
    int fln = fli + e;
    sm->fl_new[b] = fln;
    out1[b] = (float)max(fln, 1);
  }
}

// K2: gather, RPB consecutive rows per block, CH-deep load chunks.
// Weights recomputed on the fly from csum.
__global__ void __launch_bounds__(128)
k_gather(const float* __restrict__ src, const float* __restrict__ csum,
         const int* __restrict__ S, const Small* __restrict__ sm,
         float* __restrict__ out, int T, int nwgx) {
  int wg = blockIdx.x;
  int b  = wg / nwgx;
  int t0 = (wg - b * nwgx) * RPB;

  int tid = threadIdx.x;
  int fln = sm->fl_new[b];
  int flo = sm->fl_old[b];
  float sc = sm->scale[b];
  float* outb = out + ((size_t)b * T + t0) * CC;

  int nrows = T - t0; if (nrows > RPB) nrows = RPB;
  int nact = fln - t0; if (nact > RPB) nact = RPB; if (nact < 0) nact = 0;
  for (int j = nact; j < nrows; ++j)
    ((float4*)(outb + (size_t)j * CC))[tid] = make_float4(0.f, 0.f, 0.f, 0.f);
  if (nact <= 0) return;

  const int* Sb = S + b * (T + RPB + 1);
  int sarr[RPB + 1];
#pragma unroll
  for (int j = 0; j <= RPB; ++j) sarr[j] = (j <= nact) ? Sb[t0 + j] : 0x7FFFFFFF;

  int start = sarr[0];
  int end   = sarr[nact];
  const float* srcb = src + (size_t)b * SB * CC;
  const float* cb   = csum + b * SB;

  float4 acc[RPB];
#pragma unroll
  for (int j = 0; j < RPB; ++j) acc[j] = make_float4(0.f, 0.f, 0.f, 0.f);

  for (int c = start; c <= end; c += CH) {
    int nk = end - c + 1; if (nk > CH) nk = CH;
    float cv[CH], cp[CH];
    float4 sv[CH];
    float cpfirst = (c > 0) ? cb[c - 1] : 0.f;
#pragma unroll
    for (int k = 0; k < CH; ++k) {
      int i = (k < nk) ? (c + k) : end;
      cv[k] = cb[i];
      sv[k] = ((const float4*)(srcb + (size_t)i * CC))[tid];
    }
    cp[0] = cpfirst;
#pragma unroll
    for (int k = 1; k < CH; ++k) cp[k] = cv[k - 1];
#pragma unroll
    for (int k = 0; k < CH; ++k) {
      if (k < nk) {
        int i = c + k;
        float a = cv[k] - cp[k];
#pragma unroll
        for (int j = 0; j < RPB; ++j) {
          if (j < nact) {
            float tj = (float)(t0 + j);
            float w = a;
            if (i == sarr[j + 1])
              w = (rintf(cv[k]) == tj + 1.0f) ? (tj + 1.0f - cp[k]) : a;
            if (i == sarr[j] && (t0 + j) > 0)
              w = cv[k] - tj;
            bool inr = (i >= sarr[j]) && (i <= sarr[j + 1]);
            w = inr ? w : 0.f;
            acc[j].x = fmaf(w, sv[k].x, acc[j].x);
            acc[j].y = fmaf(w, sv[k].y, acc[j].y);
            acc[j].z = fmaf(w, sv[k].z, acc[j].z);
            acc[j].w = fmaf(w, sv[k].w, acc[j].w);
          }
        }
      }
    }
  }
#pragma unroll
  for (int j = 0; j < RPB; ++j) {
    if (j < nact) {
      float m = ((t0 + j) == flo) ? sc : 1.0f;
      float4 v = make_float4(acc[j].x * m, acc[j].y * m, acc[j].z * m, acc[j].w * m);
      ((float4*)(outb + (size_t)j * CC))[tid] = v;
    }
  }
}

extern "C" void kernel_launch(void* const* d_in, const int* in_sizes, int n_in,
                              void* d_out, int out_size, void* d_ws, size_t ws_size,
                              hipStream_t stream) {
  const float* src = (const float*)d_in[0];
  const void* mask = d_in[1];
  const float* alphas = (const float*)d_in[2];
  float* out = (float*)d_out;
  char* ws = (char*)d_ws;

  int T = (out_size - BB) / (BB * CC);

  float* csum = (float*)(ws + 0);          // 256 KB
  int* S      = (int*)(ws + 262144);       // BB*(T+RPB+1)*4
  Small* sm   = (Small*)(ws + 524288);

  k_scan<<<BB, 256, 0, stream>>>(alphas, mask, csum, S, sm,
                                 out + (size_t)BB * T * CC, T);
  int nwgx = (T + RPB - 1) / RPB;
  k_gather<<<BB * nwgx, 128, 0, stream>>>(src, csum, S, sm, out, T, nwgx);
}

// Round 10
// 37.565 us; speedup vs baseline: 1.1820x; 1.1820x over previous
//
#include <hip/hip_runtime.h>

#define SB 4096
#define BB 16
#define CC 512
#define RPB 4
#define CH 8

struct Small {
  int   fl_old[BB];
  int   fl_new[BB];
  float scale[BB];
};

// K1: per-batch (one 256-thr block per batch): mask-dtype detect (own 4KB
// region), masked cumsum (block scan), csum out, fire-position scatter
// S[b][r]=i (unclipped rint), llast defaults, tail=frac(total) -> scale,
// fl_old/fl_new, feat_lengths out. No cross-block dependencies.
__global__ void __launch_bounds__(256)
k_scan(const float* __restrict__ alphas, const void* __restrict__ mask,
       float* __restrict__ csum, int* __restrict__ S, Small* sm,
       float* __restrict__ out1, int T) {
  int b = blockIdx.x;
  int t = threadIdx.x;

  // mask dtype detect: scan only this batch's own uint8 region (1024 words).
  __shared__ int s_flag;
  if (t == 0) s_flag = 0;
  __syncthreads();
  {
    uint4 v = ((const uint4*)mask)[b * 256 + t];
    if ((v.x > 1u) || (v.y > 1u) || (v.z > 1u) || (v.w > 1u)) atomicOr(&s_flag, 1);
  }
  __syncthreads();
  int flag = s_flag;

  int lane = t & 63, wid = t >> 6;
  int base = t * 16;
  const float* ab = alphas + b * SB + base;
  float av[16];
#pragma unroll
  for (int k = 0; k < 16; k += 4) {
    float4 v = *(const float4*)(ab + k);
    av[k] = v.x; av[k + 1] = v.y; av[k + 2] = v.z; av[k + 3] = v.w;
  }
  unsigned mbits = 0;
  if (flag) {
    const unsigned char* mb = (const unsigned char*)mask + b * SB + base;
    uint4 mv = *(const uint4*)mb;
    unsigned mw[4] = {mv.x, mv.y, mv.z, mv.w};
#pragma unroll
    for (int k = 0; k < 16; ++k)
      if ((mw[k >> 2] >> ((k & 3) * 8)) & 0xFFu) { av[k] = 0.f; mbits |= 1u << k; }
  } else {
    const int* mi = (const int*)mask + b * SB + base;
#pragma unroll
    for (int k = 0; k < 16; ++k)
      if (mi[k]) { av[k] = 0.f; mbits |= 1u << k; }
  }

  float s = 0.f;
#pragma unroll
  for (int k = 0; k < 16; ++k) s += av[k];
  float si = s;
#pragma unroll
  for (int off = 1; off < 64; off <<= 1) {
    float v = __shfl_up(si, off);
    if (lane >= off) si += v;
  }
  __shared__ float wsum[4];
  if (lane == 63) wsum[wid] = si;
  __syncthreads();
  float woff = 0.f;
  for (int w = 0; w < wid; ++w) woff += wsum[w];
  float c = woff + (si - s);  // exclusive prefix
  float cs[16];
  float* cb = csum + b * SB + base;
#pragma unroll
  for (int k = 0; k < 16; ++k) { c += av[k]; cs[k] = c; cb[k] = c; }

  // exact previous csum: share each thread's final c via LDS
  __shared__ float cfin[256];
  __shared__ int   redl[4];
  int lmax = -1;
#pragma unroll
  for (int k = 0; k < 16; ++k) if (!((mbits >> k) & 1u)) lmax = base + k;
  cfin[t] = cs[15];
  for (int off = 32; off; off >>= 1) lmax = max(lmax, __shfl_down(lmax, off));
  if ((t & 63) == 0) redl[wid] = lmax;
  __syncthreads();
  int llast = max(max(redl[0], redl[1]), max(redl[2], redl[3]));
  float prevc = (t == 0) ? 0.f : cfin[t - 1];

  int* Sb = S + b * (T + RPB + 1);
  for (int j = t; j < T + RPB + 1; j += 256) Sb[j] = (j == 0) ? 0 : llast;
  __syncthreads();
  int p = (int)rintf(prevc);
#pragma unroll
  for (int k = 0; k < 16; ++k) {
    int r = (int)rintf(cs[k]);
    if (r != p && r < T + RPB + 1) Sb[r] = base + k;
    p = r;
  }

  if (t == 255) {
    float total = woff + si;
    float fl = floorf(total);
    float frac = total - fl;          // == tail_weights by mass conservation
    int e = (frac >= 0.5f) ? 1 : 0;
    int fli = (int)fl;
    sm->fl_old[b] = fli;
    sm->scale[b] = e ? (1.0f / frac) : 1.0f;
    int fln = fli + e;
    sm->fl_new[b] = fln;
    out1[b] = (float)max(fln, 1);
  }
}

// K2: gather, RPB consecutive rows per block, CH-deep load chunks.
// Weights recomputed on the fly from csum.
__global__ void __launch_bounds__(128)
k_gather(const float* __restrict__ src, const float* __restrict__ csum,
         const int* __restrict__ S, const Small* __restrict__ sm,
         float* __restrict__ out, int T, int nwgx) {
  int wg = blockIdx.x;
  int b  = wg / nwgx;
  int t0 = (wg - b * nwgx) * RPB;

  int tid = threadIdx.x;
  int fln = sm->fl_new[b];
  int flo = sm->fl_old[b];
  float sc = sm->scale[b];
  float* outb = out + ((size_t)b * T + t0) * CC;

  int nrows = T - t0; if (nrows > RPB) nrows = RPB;
  int nact = fln - t0; if (nact > RPB) nact = RPB; if (nact < 0) nact = 0;
  for (int j = nact; j < nrows; ++j)
    ((float4*)(outb + (size_t)j * CC))[tid] = make_float4(0.f, 0.f, 0.f, 0.f);
  if (nact <= 0) return;

  const int* Sb = S + b * (T + RPB + 1);
  int sarr[RPB + 1];
#pragma unroll
  for (int j = 0; j <= RPB; ++j) sarr[j] = (j <= nact) ? Sb[t0 + j] : 0x7FFFFFFF;

  int start = sarr[0];
  int end   = sarr[nact];
  const float* srcb = src + (size_t)b * SB * CC;
  const float* cb   = csum + b * SB;

  float4 acc[RPB];
#pragma unroll
  for (int j = 0; j < RPB; ++j) acc[j] = make_float4(0.f, 0.f, 0.f, 0.f);

  for (int c = start; c <= end; c += CH) {
    int nk = end - c + 1; if (nk > CH) nk = CH;
    float cv[CH], cp[CH];
    float4 sv[CH];
    float cpfirst = (c > 0) ? cb[c - 1] : 0.f;
#pragma unroll
    for (int k = 0; k < CH; ++k) {
      int i = (k < nk) ? (c + k) : end;
      cv[k] = cb[i];
      sv[k] = ((const float4*)(srcb + (size_t)i * CC))[tid];
    }
    cp[0] = cpfirst;
#pragma unroll
    for (int k = 1; k < CH; ++k) cp[k] = cv[k - 1];
#pragma unroll
    for (int k = 0; k < CH; ++k) {
      if (k < nk) {
        int i = c + k;
        float a = cv[k] - cp[k];
#pragma unroll
        for (int j = 0; j < RPB; ++j) {
          if (j < nact) {
            float tj = (float)(t0 + j);
            float w = a;
            if (i == sarr[j + 1])
              w = (rintf(cv[k]) == tj + 1.0f) ? (tj + 1.0f - cp[k]) : a;
            if (i == sarr[j] && (t0 + j) > 0)
              w = cv[k] - tj;
            bool inr = (i >= sarr[j]) && (i <= sarr[j + 1]);
            w = inr ? w : 0.f;
            acc[j].x = fmaf(w, sv[k].x, acc[j].x);
            acc[j].y = fmaf(w, sv[k].y, acc[j].y);
            acc[j].z = fmaf(w, sv[k].z, acc[j].z);
            acc[j].w = fmaf(w, sv[k].w, acc[j].w);
          }
        }
      }
    }
  }
#pragma unroll
  for (int j = 0; j < RPB; ++j) {
    if (j < nact) {
      float m = ((t0 + j) == flo) ? sc : 1.0f;
      float4 v = make_float4(acc[j].x * m, acc[j].y * m, acc[j].z * m, acc[j].w * m);
      ((float4*)(outb + (size_t)j * CC))[tid] = v;
    }
  }
}

extern "C" void kernel_launch(void* const* d_in, const int* in_sizes, int n_in,
                              void* d_out, int out_size, void* d_ws, size_t ws_size,
                              hipStream_t stream) {
  const float* src = (const float*)d_in[0];
  const void* mask = d_in[1];
  const float* alphas = (const float*)d_in[2];
  float* out = (float*)d_out;
  char* ws = (char*)d_ws;

  int T = (out_size - BB) / (BB * CC);

  float* csum = (float*)(ws + 0);          // 256 KB
  int* S      = (int*)(ws + 262144);       // BB*(T+RPB+1)*4
  Small* sm   = (Small*)(ws + 524288);

  k_scan<<<BB, 256, 0, stream>>>(alphas, mask, csum, S, sm,
                                 out + (size_t)BB * T * CC, T);
  int nwgx = (T + RPB - 1) / RPB;
  k_gather<<<BB * nwgx, 128, 0, stream>>>(src, csum, S, sm, out, T, nwgx);
}